// Round 13
// baseline (96.277 us; speedup 1.0000x reference)
//
#include <hip/hip_runtime.h>
#include <stdint.h>

// N=M=16384, D=64 fp32. dist[n,m] = a_sq[n] + b_sq[m] - 2 a.b; out = sum_n min_m.
// A(streamed) = TO pts in FRAGMENT order, B(resident) = -2*FROM.
// C[row=to][col=from]: min over rows is IN-LANE (tree16).
// R12 lesson (pipe audit): cinit-from-LDS doubled LDS-read traffic to
// ~20.5us/CU (> 13.7us MFMA floor) -- LDS throughput, not barriers, pinned
// main at ~37us. R13: cinit reverts to GLOBAL broadcast loads (half-uniform
// 64B -> ~1 L1 access each, L1 path is idle), hoisted to stage top so L1
// latency hides under DMA-issue + ds_reads. LDS pipe halves to ~10us < MFMA.
#define N_PTS 16384
#define TSPLITS 32
#define NBLOCKS (256 * TSPLITS / 4)  // 2048 blocks, 4 waves each
#define TO_TILES 16                  // per wave: 512 TO pts = 16 tiles of 32
#define STAGES (TO_TILES / 2)        // 8 stages of 2 tiles

typedef __attribute__((ext_vector_type(8)))  short bf16x8;
typedef __attribute__((ext_vector_type(16))) float f32x16;

__device__ __forceinline__ unsigned short f2bf(float f) {
    unsigned u = __float_as_uint(f);
    u += 0x7FFFu + ((u >> 16) & 1u);   // RNE
    return (unsigned short)(u >> 16);
}
__device__ __forceinline__ float tree16(f32x16 a) {
    float m0 = fminf(fminf(a[0],  a[1]),  a[2]);
    float m1 = fminf(fminf(a[3],  a[4]),  a[5]);
    float m2 = fminf(fminf(a[6],  a[7]),  a[8]);
    float m3 = fminf(fminf(a[9],  a[10]), a[11]);
    float m4 = fminf(fminf(a[12], a[13]), a[14]);
    float m5 = fminf(fminf(a[15], m0), m1);
    return fminf(fminf(fminf(m2, m3), m4), m5);
}

// ---------- prep: fp32 -> bf16 FRAGMENT-ORDER operands + norms ------------
__global__ __launch_bounds__(256) void prep_kernel(
        const float* __restrict__ from_pts, const float* __restrict__ to_pts,
        float* __restrict__ a_sq, float* __restrict__ bsqp,
        unsigned short* __restrict__ BfF, unsigned short* __restrict__ AtoF,
        float* __restrict__ out) {
    int gid = blockIdx.x * 256 + threadIdx.x;   // 0 .. 524287
    int row = gid >> 3;                 // 0..32767 (FROM then TO)
    int sub = gid & 7;
    bool isFrom = row < N_PTS;
    int r = row & (N_PTS - 1);
    const float* src = isFrom ? from_pts : to_pts;
    float4 v0 = ((const float4*)src)[r * 16 + sub * 2];
    float4 v1 = ((const float4*)src)[r * 16 + sub * 2 + 1];
    float s = v0.x*v0.x + v0.y*v0.y + v0.z*v0.z + v0.w*v0.w
            + v1.x*v1.x + v1.y*v1.y + v1.z*v1.z + v1.w*v1.w;
    s += __shfl_xor(s, 1); s += __shfl_xor(s, 2); s += __shfl_xor(s, 4);
    float sc = isFrom ? -2.0f : 1.0f;
    union { unsigned short u[8]; uint4 q; } w;
    w.u[0] = f2bf(v0.x * sc); w.u[1] = f2bf(v0.y * sc);
    w.u[2] = f2bf(v0.z * sc); w.u[3] = f2bf(v0.w * sc);
    w.u[4] = f2bf(v1.x * sc); w.u[5] = f2bf(v1.y * sc);
    w.u[6] = f2bf(v1.z * sc); w.u[7] = f2bf(v1.w * sc);
    int st = r >> 5;                    // subtile / tile index (0..511)
    int m  = r & 31;
    int kb = sub >> 1, h = sub & 1;
    size_t fidx = (((size_t)st * 4 + kb) * 64 + h * 32 + m) * 8;
    if (isFrom) {
        *(uint4*)(BfF + fidx) = w.q;
        if (sub == 0) a_sq[r] = s;
    } else {
        *(uint4*)(AtoF + fidx) = w.q;
        // bsq in C/D-layout order: reg=(m&3)+4*(m>>3), h-half=(m>>2)&1
        if (sub == 0)
            bsqp[st * 32 + ((m >> 2) & 1) * 16 + (m & 3) + 4 * (m >> 3)] = s;
    }
    if (gid == 0) out[0] = 0.0f;
}

// ---------- main: LDS-staged A (global_load_lds) + global-broadcast cinit -
__global__ __launch_bounds__(256, 4) void main_kernel(
        const unsigned short* __restrict__ BfF,
        const unsigned short* __restrict__ AtoF,
        const float* __restrict__ bsqp, float* __restrict__ pmin) {
    // 2 x 8KB A-stage double buffer (2 tiles/stage); NO cinit in LDS (R12!)
    __shared__ __align__(16) unsigned short abuf[2][4096];

    const int tid = threadIdx.x;
    const int lane = tid & 63;
    const int l31 = lane & 31;
    const int h   = lane >> 5;
    const int wv  = tid >> 6;           // wave 0..3
    const int wid = (blockIdx.x << 2) + wv;   // 0..8191
    const int fg  = wid & 255;          // 64 FROM pts per wave
    const int ts  = wid >> 8;           // 0..31; block's 4 waves share ts

    const bf16x8* Bv = (const bf16x8*)BfF;

    // resident FROM fragments: subtiles 2*fg, 2*fg+1 (coalesced loads)
    bf16x8 Bf0[4], Bf1[4];
    #pragma unroll
    for (int kb = 0; kb < 4; kb++) {
        Bf0[kb] = Bv[((size_t)(2 * fg)     * 4 + kb) * 64 + lane];
        Bf1[kb] = Bv[((size_t)(2 * fg + 1) * 4 + kb) * 64 + lane];
    }

    const int gtb = ts * TO_TILES;
    // Stage 2 tiles (8 fragment-blocks of 1KB); wave wv DMAs blocks 2wv,2wv+1.
    // Dest rule: wave-uniform LDS base + lane*16.
    auto stage2 = [&](int s, int buf) {
        #pragma unroll
        for (int j2 = 0; j2 < 2; j2++) {
            int j  = 2 * wv + j2;                    // 0..7
            int gt = gtb + 2 * s + (j >> 2);
            int kb = j & 3;
            const unsigned short* g = AtoF + (((size_t)gt * 4 + kb) * 64 + lane) * 8;
            unsigned short* l = &abuf[buf][j * 512];
            __builtin_amdgcn_global_load_lds(
                (const __attribute__((address_space(1))) unsigned int*)g,
                (__attribute__((address_space(3))) unsigned int*)l, 16, 0, 0);
        }
    };

    // cinit: 16 floats per (tile, half) from global -- half-uniform 64B
    // broadcast (one L1 access per load inst, keeps LDS pipe free)
    auto load_cin = [&](int gt) -> f32x16 {
        union { float4 f[4]; f32x16 v; } cu;
        const float4* cp = (const float4*)(bsqp + gt * 32 + h * 16);
        cu.f[0] = cp[0]; cu.f[1] = cp[1]; cu.f[2] = cp[2]; cu.f[3] = cp[3];
        return cu.v;
    };

    float rmin0 = 3.0e38f, rmin1 = 3.0e38f;
    auto compute = [&](int cb, int half, f32x16 cv) {
        bf16x8 A[4];
        #pragma unroll
        for (int kb = 0; kb < 4; kb++)
            A[kb] = *(const bf16x8*)&abuf[cb][(half * 4 + kb) * 512 + lane * 8];
        f32x16 acc0 = __builtin_amdgcn_mfma_f32_32x32x16_bf16(A[0], Bf0[0], cv, 0, 0, 0);
        acc0 = __builtin_amdgcn_mfma_f32_32x32x16_bf16(A[1], Bf0[1], acc0, 0, 0, 0);
        acc0 = __builtin_amdgcn_mfma_f32_32x32x16_bf16(A[2], Bf0[2], acc0, 0, 0, 0);
        acc0 = __builtin_amdgcn_mfma_f32_32x32x16_bf16(A[3], Bf0[3], acc0, 0, 0, 0);
        rmin0 = fminf(rmin0, tree16(acc0));
        f32x16 acc1 = __builtin_amdgcn_mfma_f32_32x32x16_bf16(A[0], Bf1[0], cv, 0, 0, 0);
        acc1 = __builtin_amdgcn_mfma_f32_32x32x16_bf16(A[1], Bf1[1], acc1, 0, 0, 0);
        acc1 = __builtin_amdgcn_mfma_f32_32x32x16_bf16(A[2], Bf1[2], acc1, 0, 0, 0);
        acc1 = __builtin_amdgcn_mfma_f32_32x32x16_bf16(A[3], Bf1[3], acc1, 0, 0, 0);
        rmin1 = fminf(rmin1, tree16(acc1));
    };

    stage2(0, 0);
    __syncthreads();                    // drains DMA0
    #pragma unroll 1
    for (int s = 0; s < STAGES - 1; s++) {
        // hoist cinit loads: L1 latency hides under DMA-issue + ds_reads
        f32x16 c0 = load_cin(gtb + 2 * s);
        f32x16 c1 = load_cin(gtb + 2 * s + 1);
        stage2(s + 1, (s + 1) & 1);     // 8KB DMA flies over 16 MFMAs
        compute(s & 1, 0, c0);
        compute(s & 1, 1, c1);
        __syncthreads();                // DMA s+1 landed; buf s&1 free
    }
    {
        f32x16 c0 = load_cin(gtb + TO_TILES - 2);
        f32x16 c1 = load_cin(gtb + TO_TILES - 1);
        compute((STAGES - 1) & 1, 0, c0);
        compute((STAGES - 1) & 1, 1, c1);
    }

    // cross-half min, then plain store: (ts,fg) is wave-unique -> no atomics
    rmin0 = fminf(rmin0, __shfl_xor(rmin0, 32));
    rmin1 = fminf(rmin1, __shfl_xor(rmin1, 32));
    if (lane < 32) {
        pmin[(size_t)ts * N_PTS + fg * 64 + l31]      = rmin0;
        pmin[(size_t)ts * N_PTS + fg * 64 + 32 + l31] = rmin1;
    }
}

// ---------- finish: min over 32 splits, add a_sq, global sum --------------
__global__ __launch_bounds__(256) void finish_kernel(
        const float* __restrict__ a_sq, const float* __restrict__ pmin,
        float* __restrict__ out) {
    int r = blockIdx.x * 256 + threadIdx.x;
    float m = pmin[r];
    #pragma unroll
    for (int s = 1; s < TSPLITS; s++)
        m = fminf(m, pmin[(size_t)s * N_PTS + r]);
    float v = a_sq[r] + m;
    #pragma unroll
    for (int k = 1; k < 64; k <<= 1) v += __shfl_xor(v, k);
    __shared__ float red[4];
    if ((threadIdx.x & 63) == 0) red[threadIdx.x >> 6] = v;
    __syncthreads();
    if (threadIdx.x == 0)
        atomicAdd(out, red[0] + red[1] + red[2] + red[3]);
}

extern "C" void kernel_launch(void* const* d_in, const int* in_sizes, int n_in,
                              void* d_out, int out_size, void* d_ws, size_t ws_size,
                              hipStream_t stream) {
    const float* from_pts = (const float*)d_in[0];
    const float* to_pts   = (const float*)d_in[1];
    char* ws = (char*)d_ws;
    float*          a_sq = (float*)ws;                                 //  64 KB
    float*          bsqp = (float*)(ws + (64 << 10));                  //  64 KB
    float*          pmin = (float*)(ws + (128 << 10));                 //   2 MB
    unsigned short* BfF  = (unsigned short*)(ws + (128 << 10) + (2 << 20));           // 2 MB
    unsigned short* AtoF = (unsigned short*)(ws + (128 << 10) + (2 << 20) + (2 << 20)); // 2 MB

    prep_kernel<<<(2 * N_PTS * 8) / 256, 256, 0, stream>>>(
        from_pts, to_pts, a_sq, bsqp, BfF, AtoF, (float*)d_out);
    main_kernel<<<NBLOCKS, 256, 0, stream>>>(BfF, AtoF, bsqp, pmin);
    finish_kernel<<<N_PTS / 256, 256, 0, stream>>>(a_sq, pmin, (float*)d_out);
}

// Round 14
// 94.871 us; speedup vs baseline: 1.0148x; 1.0148x over previous
//
#include <hip/hip_runtime.h>
#include <stdint.h>

// N=M=16384, D=64 fp32. dist[n,m] = a_sq[n] + b_sq[m] - 2 a.b; out = sum_n min_m.
// A(streamed) = TO pts in FRAGMENT order, B(resident) = -2*FROM.
// C[row=to][col=from]: min over rows is IN-LANE (tree16).
// R11-R13 lesson: per-stage __syncthreads+vmcnt structure pins main at ~37us
// regardless of barrier count / DMA window / cinit source -- lockstep blocks
// idle the CU at every drain. R14: STAGE ONCE, FREE-RUN. Block owns one ts,
// stages its whole 64KB A-slice to LDS (ONE barrier), then 8 waves sweep 16
// fg-groups x 16 tiles of pure ds_read+MFMA with zero barriers.
#define N_PTS 16384
#define TSPLITS 32
#define TO_TILES 16                  // 512 TO pts per ts = 16 tiles of 32
#define FGPB 16                      // fg-groups per block
#define NBLOCKS (TSPLITS * (256 / FGPB))   // 32 ts x 16 = 512 = 2 blocks/CU

typedef __attribute__((ext_vector_type(8)))  short bf16x8;
typedef __attribute__((ext_vector_type(16))) float f32x16;

__device__ __forceinline__ unsigned short f2bf(float f) {
    unsigned u = __float_as_uint(f);
    u += 0x7FFFu + ((u >> 16) & 1u);   // RNE
    return (unsigned short)(u >> 16);
}
__device__ __forceinline__ float tree16(f32x16 a) {
    float m0 = fminf(fminf(a[0],  a[1]),  a[2]);
    float m1 = fminf(fminf(a[3],  a[4]),  a[5]);
    float m2 = fminf(fminf(a[6],  a[7]),  a[8]);
    float m3 = fminf(fminf(a[9],  a[10]), a[11]);
    float m4 = fminf(fminf(a[12], a[13]), a[14]);
    float m5 = fminf(fminf(a[15], m0), m1);
    return fminf(fminf(fminf(m2, m3), m4), m5);
}

// ---------- prep: fp32 -> bf16 FRAGMENT-ORDER operands + norms ------------
__global__ __launch_bounds__(256) void prep_kernel(
        const float* __restrict__ from_pts, const float* __restrict__ to_pts,
        float* __restrict__ a_sq, float* __restrict__ bsqp,
        unsigned short* __restrict__ BfF, unsigned short* __restrict__ AtoF,
        float* __restrict__ out) {
    int gid = blockIdx.x * 256 + threadIdx.x;   // 0 .. 524287
    int row = gid >> 3;                 // 0..32767 (FROM then TO)
    int sub = gid & 7;
    bool isFrom = row < N_PTS;
    int r = row & (N_PTS - 1);
    const float* src = isFrom ? from_pts : to_pts;
    float4 v0 = ((const float4*)src)[r * 16 + sub * 2];
    float4 v1 = ((const float4*)src)[r * 16 + sub * 2 + 1];
    float s = v0.x*v0.x + v0.y*v0.y + v0.z*v0.z + v0.w*v0.w
            + v1.x*v1.x + v1.y*v1.y + v1.z*v1.z + v1.w*v1.w;
    s += __shfl_xor(s, 1); s += __shfl_xor(s, 2); s += __shfl_xor(s, 4);
    float sc = isFrom ? -2.0f : 1.0f;
    union { unsigned short u[8]; uint4 q; } w;
    w.u[0] = f2bf(v0.x * sc); w.u[1] = f2bf(v0.y * sc);
    w.u[2] = f2bf(v0.z * sc); w.u[3] = f2bf(v0.w * sc);
    w.u[4] = f2bf(v1.x * sc); w.u[5] = f2bf(v1.y * sc);
    w.u[6] = f2bf(v1.z * sc); w.u[7] = f2bf(v1.w * sc);
    int st = r >> 5;                    // subtile / tile index (0..511)
    int m  = r & 31;
    int kb = sub >> 1, h = sub & 1;
    size_t fidx = (((size_t)st * 4 + kb) * 64 + h * 32 + m) * 8;
    if (isFrom) {
        *(uint4*)(BfF + fidx) = w.q;
        if (sub == 0) a_sq[r] = s;
    } else {
        *(uint4*)(AtoF + fidx) = w.q;
        // bsq in C/D-layout order: reg=(m&3)+4*(m>>3), h-half=(m>>2)&1
        if (sub == 0)
            bsqp[st * 32 + ((m >> 2) & 1) * 16 + (m & 3) + 4 * (m >> 3)] = s;
    }
    if (gid == 0) out[0] = 0.0f;
}

// ---------- main: stage-once LDS A-slice, barrier-free MFMA sweep ---------
__global__ __launch_bounds__(512, 4) void main_kernel(
        const unsigned short* __restrict__ BfF,
        const unsigned short* __restrict__ AtoF,
        const float* __restrict__ bsqp, float* __restrict__ pmin) {
    // whole ts A-slice: 16 tiles x 4 fragment-blocks x 1KB = 64 KB
    __shared__ __align__(16) unsigned short abuf[32768];

    const int tid = threadIdx.x;
    const int lane = tid & 63;
    const int l31 = lane & 31;
    const int h   = lane >> 5;
    const int wv  = tid >> 6;           // wave 0..7
    const int ts  = blockIdx.x >> 4;    // 0..31
    const int bg  = blockIdx.x & 15;    // fg base = bg*16
    const int gtb = ts * TO_TILES;

    // stage: wave wv DMAs fragment-blocks j = 8*wv .. 8*wv+7 (1KB each,
    // dest = wave-uniform base + lane*16 per the global_load_lds rule)
    #pragma unroll
    for (int j2 = 0; j2 < 8; j2++) {
        int j  = wv * 8 + j2;                        // 0..63
        const unsigned short* g =
            AtoF + (((size_t)(gtb + (j >> 2)) * 4 + (j & 3)) * 64 + lane) * 8;
        unsigned short* l = &abuf[j * 512];
        __builtin_amdgcn_global_load_lds(
            (const __attribute__((address_space(1))) unsigned int*)g,
            (__attribute__((address_space(3))) unsigned int*)l, 16, 0, 0);
    }
    __syncthreads();                    // the ONLY barrier

    const bf16x8* Bv = (const bf16x8*)BfF;

    #pragma unroll 1
    for (int f2 = 0; f2 < 2; f2++) {
        const int fg = bg * FGPB + f2 * 8 + wv;     // wave's fg-group
        // resident FROM fragments: subtiles 2*fg, 2*fg+1 (coalesced)
        bf16x8 Bf0[4], Bf1[4];
        #pragma unroll
        for (int kb = 0; kb < 4; kb++) {
            Bf0[kb] = Bv[((size_t)(2 * fg)     * 4 + kb) * 64 + lane];
            Bf1[kb] = Bv[((size_t)(2 * fg + 1) * 4 + kb) * 64 + lane];
        }
        float rmin0 = 3.0e38f, rmin1 = 3.0e38f;

        #pragma unroll 1
        for (int t = 0; t < TO_TILES; t++) {
            bf16x8 A[4];
            #pragma unroll
            for (int kb = 0; kb < 4; kb++)
                A[kb] = *(const bf16x8*)&abuf[(t * 4 + kb) * 512 + lane * 8];
            // cinit: half-uniform 64B broadcast from global (L1-resident)
            union { float4 f[4]; f32x16 v; } cu;
            const float4* cp = (const float4*)(bsqp + (gtb + t) * 32 + h * 16);
            cu.f[0] = cp[0]; cu.f[1] = cp[1]; cu.f[2] = cp[2]; cu.f[3] = cp[3];

            f32x16 acc0 = __builtin_amdgcn_mfma_f32_32x32x16_bf16(A[0], Bf0[0], cu.v, 0, 0, 0);
            acc0 = __builtin_amdgcn_mfma_f32_32x32x16_bf16(A[1], Bf0[1], acc0, 0, 0, 0);
            acc0 = __builtin_amdgcn_mfma_f32_32x32x16_bf16(A[2], Bf0[2], acc0, 0, 0, 0);
            acc0 = __builtin_amdgcn_mfma_f32_32x32x16_bf16(A[3], Bf0[3], acc0, 0, 0, 0);
            rmin0 = fminf(rmin0, tree16(acc0));
            f32x16 acc1 = __builtin_amdgcn_mfma_f32_32x32x16_bf16(A[0], Bf1[0], cu.v, 0, 0, 0);
            acc1 = __builtin_amdgcn_mfma_f32_32x32x16_bf16(A[1], Bf1[1], acc1, 0, 0, 0);
            acc1 = __builtin_amdgcn_mfma_f32_32x32x16_bf16(A[2], Bf1[2], acc1, 0, 0, 0);
            acc1 = __builtin_amdgcn_mfma_f32_32x32x16_bf16(A[3], Bf1[3], acc1, 0, 0, 0);
            rmin1 = fminf(rmin1, tree16(acc1));
        }

        // cross-half min, plain store: (ts,fg) wave-unique -> no atomics
        rmin0 = fminf(rmin0, __shfl_xor(rmin0, 32));
        rmin1 = fminf(rmin1, __shfl_xor(rmin1, 32));
        if (lane < 32) {
            pmin[(size_t)ts * N_PTS + fg * 64 + l31]      = rmin0;
            pmin[(size_t)ts * N_PTS + fg * 64 + 32 + l31] = rmin1;
        }
    }
}

// ---------- finish: min over 32 splits, add a_sq, global sum --------------
__global__ __launch_bounds__(256) void finish_kernel(
        const float* __restrict__ a_sq, const float* __restrict__ pmin,
        float* __restrict__ out) {
    int r = blockIdx.x * 256 + threadIdx.x;
    float m = pmin[r];
    #pragma unroll
    for (int s = 1; s < TSPLITS; s++)
        m = fminf(m, pmin[(size_t)s * N_PTS + r]);
    float v = a_sq[r] + m;
    #pragma unroll
    for (int k = 1; k < 64; k <<= 1) v += __shfl_xor(v, k);
    __shared__ float red[4];
    if ((threadIdx.x & 63) == 0) red[threadIdx.x >> 6] = v;
    __syncthreads();
    if (threadIdx.x == 0)
        atomicAdd(out, red[0] + red[1] + red[2] + red[3]);
}

extern "C" void kernel_launch(void* const* d_in, const int* in_sizes, int n_in,
                              void* d_out, int out_size, void* d_ws, size_t ws_size,
                              hipStream_t stream) {
    const float* from_pts = (const float*)d_in[0];
    const float* to_pts   = (const float*)d_in[1];
    char* ws = (char*)d_ws;
    float*          a_sq = (float*)ws;                                 //  64 KB
    float*          bsqp = (float*)(ws + (64 << 10));                  //  64 KB
    float*          pmin = (float*)(ws + (128 << 10));                 //   2 MB
    unsigned short* BfF  = (unsigned short*)(ws + (128 << 10) + (2 << 20));           // 2 MB
    unsigned short* AtoF = (unsigned short*)(ws + (128 << 10) + (2 << 20) + (2 << 20)); // 2 MB

    prep_kernel<<<(2 * N_PTS * 8) / 256, 256, 0, stream>>>(
        from_pts, to_pts, a_sq, bsqp, BfF, AtoF, (float*)d_out);
    main_kernel<<<NBLOCKS, 512, 0, stream>>>(BfF, AtoF, bsqp, pmin);
    finish_kernel<<<N_PTS / 256, 256, 0, stream>>>(a_sq, pmin, (float*)d_out);
}

// Round 15
// 83.416 us; speedup vs baseline: 1.1542x; 1.1373x over previous
//
#include <hip/hip_runtime.h>
#include <stdint.h>

// N=M=16384, D=64 fp32. dist[n,m]=a_sq[n]+b_sq[m]-2ab; out = sum_n min_m.
// R11-R14 lesson: bf16 MFMA main is pinned at ~37us == the m97 source-level
// HIP plateau (~930 TF, 37% dense) regardless of staging structure. R15:
// cut MFMA work itself -- i8 K=32 MFMA at 1.85x bf16 rate, exact integer
// score I = 128*bsq - 256*(a.b) seeded via the i32 accumulator; row-min is
// an integer tree16. Only input quantization (+-1/32) adds error:
// sigma~0.33/distance, total ~1-2k << 20.8k threshold.
#define N_PTS 16384
#define TSPLITS 32
#define TO_TILES 16                  // 512 TO pts per ts = 16 tiles of 32
#define FGPB 16                      // fg-groups per block
#define NBLOCKS (TSPLITS * (256 / FGPB))   // 512 blocks = 2/CU

typedef __attribute__((ext_vector_type(4)))  int i32x4;
typedef __attribute__((ext_vector_type(16))) int i32x16;

__device__ __forceinline__ int imin(int a, int b) { return a < b ? a : b; }
__device__ __forceinline__ int itree16(i32x16 a) {
    int m0 = imin(imin(a[0],  a[1]),  a[2]);
    int m1 = imin(imin(a[3],  a[4]),  a[5]);
    int m2 = imin(imin(a[6],  a[7]),  a[8]);
    int m3 = imin(imin(a[9],  a[10]), a[11]);
    int m4 = imin(imin(a[12], a[13]), a[14]);
    int m5 = imin(imin(a[15], m0), m1);
    return imin(imin(imin(m2, m3), m4), m5);
}
__device__ __forceinline__ int q8(float x) {   // round-nearest, clamp
    int q = __float2int_rn(x);
    return q < -127 ? -127 : (q > 127 ? 127 : q);
}

// ---------- prep: fp32 -> i8 FRAGMENT-ORDER operands + norms --------------
// thread (row, sub): sub in 0..7 owns dims [8sub, 8sub+8). Fragment layout
// for mfma_i32_32x32x32_i8 (A regs v[0:3] = 16 bytes = k-sub 16h..16h+15):
// chunk(st, kb, lane=h*32+m) of 16B; dim d -> kb=d>>5, h=(d>>4)&1, j=d&15.
__global__ __launch_bounds__(256) void prep_kernel(
        const float* __restrict__ from_pts, const float* __restrict__ to_pts,
        float* __restrict__ a_sq, int* __restrict__ bsqi,
        char* __restrict__ BfQ, char* __restrict__ AtoQ,
        float* __restrict__ out) {
    int gid = blockIdx.x * 256 + threadIdx.x;   // 0 .. 524287
    int row = gid >> 3;                 // 0..32767 (FROM then TO)
    int sub = gid & 7;
    bool isFrom = row < N_PTS;
    int r = row & (N_PTS - 1);
    const float* src = isFrom ? from_pts : to_pts;
    float4 v0 = ((const float4*)src)[r * 16 + sub * 2];
    float4 v1 = ((const float4*)src)[r * 16 + sub * 2 + 1];
    float s = v0.x*v0.x + v0.y*v0.y + v0.z*v0.z + v0.w*v0.w
            + v1.x*v1.x + v1.y*v1.y + v1.z*v1.z + v1.w*v1.w;
    s += __shfl_xor(s, 1); s += __shfl_xor(s, 2); s += __shfl_xor(s, 4);
    float sc = isFrom ? -16.0f : 16.0f;  // FROM carries the minus sign
    int q0 = q8(v0.x*sc), q1 = q8(v0.y*sc), q2 = q8(v0.z*sc), q3 = q8(v0.w*sc);
    int q4 = q8(v1.x*sc), q5 = q8(v1.y*sc), q6 = q8(v1.z*sc), q7 = q8(v1.w*sc);
    int2 w;
    w.x = (q0 & 255) | ((q1 & 255) << 8) | ((q2 & 255) << 16) | (q3 << 24);
    w.y = (q4 & 255) | ((q5 & 255) << 8) | ((q6 & 255) << 16) | (q7 << 24);
    int st = r >> 5;                    // subtile / tile index (0..511)
    int m  = r & 31;
    int kb = sub >> 2, h = (sub >> 1) & 1, half8 = sub & 1;
    size_t off = (((size_t)st * 2 + kb) * 64 + h * 32 + m) * 16 + 8 * half8;
    if (isFrom) {
        *(int2*)(BfQ + off) = w;
        if (sub == 0) a_sq[r] = s;
    } else {
        *(int2*)(AtoQ + off) = w;
        // bsqi = round(128*bsq) in C/D-layout order
        if (sub == 0)
            bsqi[st * 32 + ((m >> 2) & 1) * 16 + (m & 3) + 4 * (m >> 3)] =
                __float2int_rn(128.0f * s);
    }
    if (gid == 0) out[0] = 0.0f;
}

// ---------- main: stage-once LDS A-slice, barrier-free i8 MFMA sweep ------
__global__ __launch_bounds__(512, 4) void main_kernel(
        const char* __restrict__ BfQ, const char* __restrict__ AtoQ,
        const int* __restrict__ bsqi, int* __restrict__ pmin) {
    // whole ts A-slice: 16 tiles x 2 kb-chunks x 1KB = 32 KB
    __shared__ __align__(16) char abuf[32768];

    const int tid = threadIdx.x;
    const int lane = tid & 63;
    const int l31 = lane & 31;
    const int h   = lane >> 5;
    const int wv  = tid >> 6;           // wave 0..7
    const int ts  = blockIdx.x >> 4;    // 0..31
    const int bg  = blockIdx.x & 15;
    const int gtb = ts * TO_TILES;

    // stage: 32 chunks of 1KB; wave wv DMAs chunks 4wv..4wv+3
    // (dest = wave-uniform base + lane*16 per the global_load_lds rule)
    #pragma unroll
    for (int j2 = 0; j2 < 4; j2++) {
        int j = wv * 4 + j2;                         // 0..31
        const char* g = AtoQ +
            (((size_t)(gtb + (j >> 1)) * 2 + (j & 1)) * 64 + lane) * 16;
        char* l = &abuf[j * 1024];
        __builtin_amdgcn_global_load_lds(
            (const __attribute__((address_space(1))) unsigned int*)g,
            (__attribute__((address_space(3))) unsigned int*)l, 16, 0, 0);
    }
    __syncthreads();                    // the ONLY barrier

    #pragma unroll 1
    for (int f2 = 0; f2 < 2; f2++) {
        const int fg = bg * FGPB + f2 * 8 + wv;     // wave's fg-group
        // resident FROM fragments: subtiles 2fg, 2fg+1 x 2 k-chunks
        i32x4 Bf0[2], Bf1[2];
        #pragma unroll
        for (int kb = 0; kb < 2; kb++) {
            Bf0[kb] = *(const i32x4*)(BfQ + (((size_t)(2 * fg)     * 2 + kb) * 64 + lane) * 16);
            Bf1[kb] = *(const i32x4*)(BfQ + (((size_t)(2 * fg + 1) * 2 + kb) * 64 + lane) * 16);
        }
        int rmin0 = 0x7FFFFFFF, rmin1 = 0x7FFFFFFF;

        #pragma unroll 1
        for (int t = 0; t < TO_TILES; t++) {
            i32x4 A0 = *(const i32x4*)&abuf[((t * 2 + 0) * 64 + lane) * 16];
            i32x4 A1 = *(const i32x4*)&abuf[((t * 2 + 1) * 64 + lane) * 16];
            // cinit = 128*bsq of this tile's 16 rows (half-uniform 64B)
            union { int4 f[4]; i32x16 v; } cu;
            const int4* cp = (const int4*)(bsqi + (gtb + t) * 32 + h * 16);
            cu.f[0] = cp[0]; cu.f[1] = cp[1]; cu.f[2] = cp[2]; cu.f[3] = cp[3];

            i32x16 acc0 = __builtin_amdgcn_mfma_i32_32x32x32_i8(A0, Bf0[0], cu.v, 0, 0, 0);
            i32x16 acc1 = __builtin_amdgcn_mfma_i32_32x32x32_i8(A0, Bf1[0], cu.v, 0, 0, 0);
            acc0 = __builtin_amdgcn_mfma_i32_32x32x32_i8(A1, Bf0[1], acc0, 0, 0, 0);
            acc1 = __builtin_amdgcn_mfma_i32_32x32x32_i8(A1, Bf1[1], acc1, 0, 0, 0);
            rmin0 = imin(rmin0, itree16(acc0));
            rmin1 = imin(rmin1, itree16(acc1));
        }

        // cross-half min, plain store: (ts,fg) wave-unique -> no atomics
        rmin0 = imin(rmin0, __shfl_xor(rmin0, 32));
        rmin1 = imin(rmin1, __shfl_xor(rmin1, 32));
        if (lane < 32) {
            pmin[(size_t)ts * N_PTS + fg * 64 + l31]      = rmin0;
            pmin[(size_t)ts * N_PTS + fg * 64 + 32 + l31] = rmin1;
        }
    }
}

// ---------- finish: min over 32 splits, add a_sq, global sum --------------
__global__ __launch_bounds__(256) void finish_kernel(
        const float* __restrict__ a_sq, const int* __restrict__ pmin,
        float* __restrict__ out) {
    int r = blockIdx.x * 256 + threadIdx.x;
    int m = pmin[r];
    #pragma unroll
    for (int s = 1; s < TSPLITS; s++)
        m = imin(m, pmin[(size_t)s * N_PTS + r]);
    float v = a_sq[r] + (float)m * 0.0078125f;   // /128
    #pragma unroll
    for (int k = 1; k < 64; k <<= 1) v += __shfl_xor(v, k);
    __shared__ float red[4];
    if ((threadIdx.x & 63) == 0) red[threadIdx.x >> 6] = v;
    __syncthreads();
    if (threadIdx.x == 0)
        atomicAdd(out, red[0] + red[1] + red[2] + red[3]);
}

extern "C" void kernel_launch(void* const* d_in, const int* in_sizes, int n_in,
                              void* d_out, int out_size, void* d_ws, size_t ws_size,
                              hipStream_t stream) {
    const float* from_pts = (const float*)d_in[0];
    const float* to_pts   = (const float*)d_in[1];
    char* ws = (char*)d_ws;
    float* a_sq = (float*)ws;                                  //  64 KB
    int*   bsqi = (int*)(ws + (64 << 10));                     //  64 KB
    int*   pmin = (int*)(ws + (128 << 10));                    //   2 MB
    char*  BfQ  = ws + (128 << 10) + (2 << 20);                //   1 MB
    char*  AtoQ = ws + (128 << 10) + (3 << 20);                //   1 MB

    prep_kernel<<<(2 * N_PTS * 8) / 256, 256, 0, stream>>>(
        from_pts, to_pts, a_sq, bsqi, BfQ, AtoQ, (float*)d_out);
    main_kernel<<<NBLOCKS, 512, 0, stream>>>(BfQ, AtoQ, bsqi, pmin);
    finish_kernel<<<N_PTS / 256, 256, 0, stream>>>(a_sq, pmin, (float*)d_out);
}

// Round 16
// 79.185 us; speedup vs baseline: 1.2159x; 1.0534x over previous
//
#include <hip/hip_runtime.h>
#include <stdint.h>

// N=M=16384, D=64 fp32. dist[n,m]=a_sq[n]+b_sq[m]-2ab; out = sum_n min_m.
// R15: i8 K=32 MFMA exact-integer path: main ~38 -> ~27us (passed, abs 0).
// R16: fold BOTH fg-groups into one tile loop (possible because i8 B-frags
// are half bf16 size): 16 iters x 8 MFMA instead of 32 x 4 -- per-tile
// ds_read/cinit/waitcnt overhead amortized 2x. Floor: 7.8us of i8 pipe.
#define N_PTS 16384
#define TSPLITS 32
#define TO_TILES 16                  // 512 TO pts per ts = 16 tiles of 32
#define FGPB 16                      // fg-groups per block
#define NBLOCKS (TSPLITS * (256 / FGPB))   // 512 blocks = 2/CU

typedef __attribute__((ext_vector_type(4)))  int i32x4;
typedef __attribute__((ext_vector_type(16))) int i32x16;

__device__ __forceinline__ int imin(int a, int b) { return a < b ? a : b; }
__device__ __forceinline__ int itree16(i32x16 a) {
    int m0 = imin(imin(a[0],  a[1]),  a[2]);
    int m1 = imin(imin(a[3],  a[4]),  a[5]);
    int m2 = imin(imin(a[6],  a[7]),  a[8]);
    int m3 = imin(imin(a[9],  a[10]), a[11]);
    int m4 = imin(imin(a[12], a[13]), a[14]);
    int m5 = imin(imin(a[15], m0), m1);
    return imin(imin(imin(m2, m3), m4), m5);
}
__device__ __forceinline__ int q8(float x) {   // round-nearest, clamp
    int q = __float2int_rn(x);
    return q < -127 ? -127 : (q > 127 ? 127 : q);
}

// ---------- prep: fp32 -> i8 FRAGMENT-ORDER operands + norms --------------
// Fragment layout for mfma_i32_32x32x32_i8: chunk(st, kb, lane=h*32+m) of
// 16B; dim d -> kb=d>>5, h=(d>>4)&1, j=d&15.
__global__ __launch_bounds__(256) void prep_kernel(
        const float* __restrict__ from_pts, const float* __restrict__ to_pts,
        float* __restrict__ a_sq, int* __restrict__ bsqi,
        char* __restrict__ BfQ, char* __restrict__ AtoQ,
        float* __restrict__ out) {
    int gid = blockIdx.x * 256 + threadIdx.x;   // 0 .. 524287
    int row = gid >> 3;                 // 0..32767 (FROM then TO)
    int sub = gid & 7;
    bool isFrom = row < N_PTS;
    int r = row & (N_PTS - 1);
    const float* src = isFrom ? from_pts : to_pts;
    float4 v0 = ((const float4*)src)[r * 16 + sub * 2];
    float4 v1 = ((const float4*)src)[r * 16 + sub * 2 + 1];
    float s = v0.x*v0.x + v0.y*v0.y + v0.z*v0.z + v0.w*v0.w
            + v1.x*v1.x + v1.y*v1.y + v1.z*v1.z + v1.w*v1.w;
    s += __shfl_xor(s, 1); s += __shfl_xor(s, 2); s += __shfl_xor(s, 4);
    float sc = isFrom ? -16.0f : 16.0f;  // FROM carries the minus sign
    int q0 = q8(v0.x*sc), q1 = q8(v0.y*sc), q2 = q8(v0.z*sc), q3 = q8(v0.w*sc);
    int q4 = q8(v1.x*sc), q5 = q8(v1.y*sc), q6 = q8(v1.z*sc), q7 = q8(v1.w*sc);
    int2 w;
    w.x = (q0 & 255) | ((q1 & 255) << 8) | ((q2 & 255) << 16) | (q3 << 24);
    w.y = (q4 & 255) | ((q5 & 255) << 8) | ((q6 & 255) << 16) | (q7 << 24);
    int st = r >> 5;                    // subtile / tile index (0..511)
    int m  = r & 31;
    int kb = sub >> 2, h = (sub >> 1) & 1, half8 = sub & 1;
    size_t off = (((size_t)st * 2 + kb) * 64 + h * 32 + m) * 16 + 8 * half8;
    if (isFrom) {
        *(int2*)(BfQ + off) = w;
        if (sub == 0) a_sq[r] = s;
    } else {
        *(int2*)(AtoQ + off) = w;
        // bsqi = round(128*bsq) in C/D-layout order
        if (sub == 0)
            bsqi[st * 32 + ((m >> 2) & 1) * 16 + (m & 3) + 4 * (m >> 3)] =
                __float2int_rn(128.0f * s);
    }
    if (gid == 0) out[0] = 0.0f;
}

// ---------- main: stage-once LDS, barrier-free, 2-fg-folded i8 sweep ------
__global__ __launch_bounds__(512, 4) void main_kernel(
        const char* __restrict__ BfQ, const char* __restrict__ AtoQ,
        const int* __restrict__ bsqi, int* __restrict__ pmin) {
    // whole ts A-slice: 16 tiles x 2 kb-chunks x 1KB = 32 KB
    __shared__ __align__(16) char abuf[32768];

    const int tid = threadIdx.x;
    const int lane = tid & 63;
    const int l31 = lane & 31;
    const int h   = lane >> 5;
    const int wv  = tid >> 6;           // wave 0..7
    const int ts  = blockIdx.x >> 4;    // 0..31
    const int bg  = blockIdx.x & 15;
    const int gtb = ts * TO_TILES;

    // stage: 32 chunks of 1KB; wave wv DMAs chunks 4wv..4wv+3
    // (dest = wave-uniform base + lane*16 per the global_load_lds rule)
    #pragma unroll
    for (int j2 = 0; j2 < 4; j2++) {
        int j = wv * 4 + j2;                         // 0..31
        const char* g = AtoQ +
            (((size_t)(gtb + (j >> 1)) * 2 + (j & 1)) * 64 + lane) * 16;
        char* l = &abuf[j * 1024];
        __builtin_amdgcn_global_load_lds(
            (const __attribute__((address_space(1))) unsigned int*)g,
            (__attribute__((address_space(3))) unsigned int*)l, 16, 0, 0);
    }
    __syncthreads();                    // the ONLY barrier

    // both fg-groups resident: fgA = bg*16+wv, fgB = fgA+8.
    // 4 B-subtiles x 2 k-chunks (i32x4 each) = 32 VGPRs.
    const int fgA = bg * FGPB + wv;
    const int fgB = fgA + 8;
    i32x4 B00[2], B01[2], B10[2], B11[2];
    #pragma unroll
    for (int kb = 0; kb < 2; kb++) {
        B00[kb] = *(const i32x4*)(BfQ + (((size_t)(2 * fgA)     * 2 + kb) * 64 + lane) * 16);
        B01[kb] = *(const i32x4*)(BfQ + (((size_t)(2 * fgA + 1) * 2 + kb) * 64 + lane) * 16);
        B10[kb] = *(const i32x4*)(BfQ + (((size_t)(2 * fgB)     * 2 + kb) * 64 + lane) * 16);
        B11[kb] = *(const i32x4*)(BfQ + (((size_t)(2 * fgB + 1) * 2 + kb) * 64 + lane) * 16);
    }
    int rmin00 = 0x7FFFFFFF, rmin01 = 0x7FFFFFFF;
    int rmin10 = 0x7FFFFFFF, rmin11 = 0x7FFFFFFF;

    #pragma unroll 1
    for (int t = 0; t < TO_TILES; t++) {
        i32x4 A0 = *(const i32x4*)&abuf[((t * 2 + 0) * 64 + lane) * 16];
        i32x4 A1 = *(const i32x4*)&abuf[((t * 2 + 1) * 64 + lane) * 16];
        // cinit = 128*bsq of this tile's 16 rows (half-uniform 64B) --
        // loaded ONCE per tile, reused by all 4 chains
        union { int4 f[4]; i32x16 v; } cu;
        const int4* cp = (const int4*)(bsqi + (gtb + t) * 32 + h * 16);
        cu.f[0] = cp[0]; cu.f[1] = cp[1]; cu.f[2] = cp[2]; cu.f[3] = cp[3];

        i32x16 c0 = __builtin_amdgcn_mfma_i32_32x32x32_i8(A0, B00[0], cu.v, 0, 0, 0);
        i32x16 c1 = __builtin_amdgcn_mfma_i32_32x32x32_i8(A0, B01[0], cu.v, 0, 0, 0);
        c0 = __builtin_amdgcn_mfma_i32_32x32x32_i8(A1, B00[1], c0, 0, 0, 0);
        c1 = __builtin_amdgcn_mfma_i32_32x32x32_i8(A1, B01[1], c1, 0, 0, 0);
        rmin00 = imin(rmin00, itree16(c0));
        rmin01 = imin(rmin01, itree16(c1));
        i32x16 c2 = __builtin_amdgcn_mfma_i32_32x32x32_i8(A0, B10[0], cu.v, 0, 0, 0);
        i32x16 c3 = __builtin_amdgcn_mfma_i32_32x32x32_i8(A0, B11[0], cu.v, 0, 0, 0);
        c2 = __builtin_amdgcn_mfma_i32_32x32x32_i8(A1, B10[1], c2, 0, 0, 0);
        c3 = __builtin_amdgcn_mfma_i32_32x32x32_i8(A1, B11[1], c3, 0, 0, 0);
        rmin10 = imin(rmin10, itree16(c2));
        rmin11 = imin(rmin11, itree16(c3));
    }

    // cross-half min, plain stores: (ts,fg) wave-unique -> no atomics
    rmin00 = imin(rmin00, __shfl_xor(rmin00, 32));
    rmin01 = imin(rmin01, __shfl_xor(rmin01, 32));
    rmin10 = imin(rmin10, __shfl_xor(rmin10, 32));
    rmin11 = imin(rmin11, __shfl_xor(rmin11, 32));
    if (lane < 32) {
        pmin[(size_t)ts * N_PTS + fgA * 64 + l31]      = rmin00;
        pmin[(size_t)ts * N_PTS + fgA * 64 + 32 + l31] = rmin01;
        pmin[(size_t)ts * N_PTS + fgB * 64 + l31]      = rmin10;
        pmin[(size_t)ts * N_PTS + fgB * 64 + 32 + l31] = rmin11;
    }
}

// ---------- finish: min over 32 splits, add a_sq, global sum --------------
__global__ __launch_bounds__(256) void finish_kernel(
        const float* __restrict__ a_sq, const int* __restrict__ pmin,
        float* __restrict__ out) {
    int r = blockIdx.x * 256 + threadIdx.x;
    int m = pmin[r];
    #pragma unroll
    for (int s = 1; s < TSPLITS; s++)
        m = imin(m, pmin[(size_t)s * N_PTS + r]);
    float v = a_sq[r] + (float)m * 0.0078125f;   // /128
    #pragma unroll
    for (int k = 1; k < 64; k <<= 1) v += __shfl_xor(v, k);
    __shared__ float red[4];
    if ((threadIdx.x & 63) == 0) red[threadIdx.x >> 6] = v;
    __syncthreads();
    if (threadIdx.x == 0)
        atomicAdd(out, red[0] + red[1] + red[2] + red[3]);
}

extern "C" void kernel_launch(void* const* d_in, const int* in_sizes, int n_in,
                              void* d_out, int out_size, void* d_ws, size_t ws_size,
                              hipStream_t stream) {
    const float* from_pts = (const float*)d_in[0];
    const float* to_pts   = (const float*)d_in[1];
    char* ws = (char*)d_ws;
    float* a_sq = (float*)ws;                                  //  64 KB
    int*   bsqi = (int*)(ws + (64 << 10));                     //  64 KB
    int*   pmin = (int*)(ws + (128 << 10));                    //   2 MB
    char*  BfQ  = ws + (128 << 10) + (2 << 20);                //   1 MB
    char*  AtoQ = ws + (128 << 10) + (3 << 20);                //   1 MB

    prep_kernel<<<(2 * N_PTS * 8) / 256, 256, 0, stream>>>(
        from_pts, to_pts, a_sq, bsqi, BfQ, AtoQ, (float*)d_out);
    main_kernel<<<NBLOCKS, 512, 0, stream>>>(BfQ, AtoQ, bsqi, pmin);
    finish_kernel<<<N_PTS / 256, 256, 0, stream>>>(a_sq, pmin, (float*)d_out);
}

// Round 17
// 78.923 us; speedup vs baseline: 1.2199x; 1.0033x over previous
//
#include <hip/hip_runtime.h>
#include <stdint.h>

// N=M=16384, D=64 fp32. dist[n,m]=a_sq[n]+b_sq[m]-2ab; out = sum_n min_m.
// R15: i8 exact-integer MFMA (main ~38->~27us). R16: 2-fg fold (->~25us).
// R17: kill the in-loop dependency waits -- all 8 waves leave the barrier
// lockstep and stall on A-lgkmcnt + cinit-vmcnt simultaneously (MFMA pipe
// ~31% despite 4 waves/SIMD). Step-2 role-swap prefetch of A (ds_read) and
// cinit (global) one tile ahead; ~126 regs, fits the (512,4) 128-VGPR cap.
#define N_PTS 16384
#define TSPLITS 32
#define TO_TILES 16                  // 512 TO pts per ts = 16 tiles of 32
#define FGPB 16                      // fg-groups per block
#define NBLOCKS (TSPLITS * (256 / FGPB))   // 512 blocks = 2/CU

typedef __attribute__((ext_vector_type(4)))  int i32x4;
typedef __attribute__((ext_vector_type(16))) int i32x16;

__device__ __forceinline__ int imin(int a, int b) { return a < b ? a : b; }
__device__ __forceinline__ int itree16(i32x16 a) {
    int m0 = imin(imin(a[0],  a[1]),  a[2]);
    int m1 = imin(imin(a[3],  a[4]),  a[5]);
    int m2 = imin(imin(a[6],  a[7]),  a[8]);
    int m3 = imin(imin(a[9],  a[10]), a[11]);
    int m4 = imin(imin(a[12], a[13]), a[14]);
    int m5 = imin(imin(a[15], m0), m1);
    return imin(imin(imin(m2, m3), m4), m5);
}
__device__ __forceinline__ int q8(float x) {   // round-nearest, clamp
    int q = __float2int_rn(x);
    return q < -127 ? -127 : (q > 127 ? 127 : q);
}

// ---------- prep: fp32 -> i8 FRAGMENT-ORDER operands + norms --------------
// Fragment layout for mfma_i32_32x32x32_i8: chunk(st, kb, lane=h*32+m) of
// 16B; dim d -> kb=d>>5, h=(d>>4)&1, j=d&15.
__global__ __launch_bounds__(256) void prep_kernel(
        const float* __restrict__ from_pts, const float* __restrict__ to_pts,
        float* __restrict__ a_sq, int* __restrict__ bsqi,
        char* __restrict__ BfQ, char* __restrict__ AtoQ,
        float* __restrict__ out) {
    int gid = blockIdx.x * 256 + threadIdx.x;   // 0 .. 524287
    int row = gid >> 3;                 // 0..32767 (FROM then TO)
    int sub = gid & 7;
    bool isFrom = row < N_PTS;
    int r = row & (N_PTS - 1);
    const float* src = isFrom ? from_pts : to_pts;
    float4 v0 = ((const float4*)src)[r * 16 + sub * 2];
    float4 v1 = ((const float4*)src)[r * 16 + sub * 2 + 1];
    float s = v0.x*v0.x + v0.y*v0.y + v0.z*v0.z + v0.w*v0.w
            + v1.x*v1.x + v1.y*v1.y + v1.z*v1.z + v1.w*v1.w;
    s += __shfl_xor(s, 1); s += __shfl_xor(s, 2); s += __shfl_xor(s, 4);
    float sc = isFrom ? -16.0f : 16.0f;  // FROM carries the minus sign
    int q0 = q8(v0.x*sc), q1 = q8(v0.y*sc), q2 = q8(v0.z*sc), q3 = q8(v0.w*sc);
    int q4 = q8(v1.x*sc), q5 = q8(v1.y*sc), q6 = q8(v1.z*sc), q7 = q8(v1.w*sc);
    int2 w;
    w.x = (q0 & 255) | ((q1 & 255) << 8) | ((q2 & 255) << 16) | (q3 << 24);
    w.y = (q4 & 255) | ((q5 & 255) << 8) | ((q6 & 255) << 16) | (q7 << 24);
    int st = r >> 5;                    // subtile / tile index (0..511)
    int m  = r & 31;
    int kb = sub >> 2, h = (sub >> 1) & 1, half8 = sub & 1;
    size_t off = (((size_t)st * 2 + kb) * 64 + h * 32 + m) * 16 + 8 * half8;
    if (isFrom) {
        *(int2*)(BfQ + off) = w;
        if (sub == 0) a_sq[r] = s;
    } else {
        *(int2*)(AtoQ + off) = w;
        // bsqi = round(128*bsq) in C/D-layout order
        if (sub == 0)
            bsqi[st * 32 + ((m >> 2) & 1) * 16 + (m & 3) + 4 * (m >> 3)] =
                __float2int_rn(128.0f * s);
    }
    if (gid == 0) out[0] = 0.0f;
}

// ---------- main: stage-once LDS, prefetched barrier-free i8 sweep --------
__global__ __launch_bounds__(512, 4) void main_kernel(
        const char* __restrict__ BfQ, const char* __restrict__ AtoQ,
        const int* __restrict__ bsqi, int* __restrict__ pmin) {
    // whole ts A-slice: 16 tiles x 2 kb-chunks x 1KB = 32 KB
    __shared__ __align__(16) char abuf[32768];

    const int tid = threadIdx.x;
    const int lane = tid & 63;
    const int l31 = lane & 31;
    const int h   = lane >> 5;
    const int wv  = tid >> 6;           // wave 0..7
    const int ts  = blockIdx.x >> 4;    // 0..31
    const int bg  = blockIdx.x & 15;
    const int gtb = ts * TO_TILES;

    // stage: 32 chunks of 1KB; wave wv DMAs chunks 4wv..4wv+3
    // (dest = wave-uniform base + lane*16 per the global_load_lds rule)
    #pragma unroll
    for (int j2 = 0; j2 < 4; j2++) {
        int j = wv * 4 + j2;                         // 0..31
        const char* g = AtoQ +
            (((size_t)(gtb + (j >> 1)) * 2 + (j & 1)) * 64 + lane) * 16;
        char* l = &abuf[j * 1024];
        __builtin_amdgcn_global_load_lds(
            (const __attribute__((address_space(1))) unsigned int*)g,
            (__attribute__((address_space(3))) unsigned int*)l, 16, 0, 0);
    }
    __syncthreads();                    // the ONLY barrier

    // both fg-groups resident: fgA = bg*16+wv, fgB = fgA+8 (32 VGPRs)
    const int fgA = bg * FGPB + wv;
    const int fgB = fgA + 8;
    i32x4 B00[2], B01[2], B10[2], B11[2];
    #pragma unroll
    for (int kb = 0; kb < 2; kb++) {
        B00[kb] = *(const i32x4*)(BfQ + (((size_t)(2 * fgA)     * 2 + kb) * 64 + lane) * 16);
        B01[kb] = *(const i32x4*)(BfQ + (((size_t)(2 * fgA + 1) * 2 + kb) * 64 + lane) * 16);
        B10[kb] = *(const i32x4*)(BfQ + (((size_t)(2 * fgB)     * 2 + kb) * 64 + lane) * 16);
        B11[kb] = *(const i32x4*)(BfQ + (((size_t)(2 * fgB + 1) * 2 + kb) * 64 + lane) * 16);
    }
    int rmin00 = 0x7FFFFFFF, rmin01 = 0x7FFFFFFF;
    int rmin10 = 0x7FFFFFFF, rmin11 = 0x7FFFFFFF;

    // ---- step-2 role-swap pipeline: A (LDS) + cinit (global) 1 tile ahead
    #define LOADT(T, A, CU)                                                     \
        {                                                                       \
            int t_ = (T);                                                       \
            A[0] = *(const i32x4*)&abuf[((t_ * 2 + 0) * 64 + lane) * 16];       \
            A[1] = *(const i32x4*)&abuf[((t_ * 2 + 1) * 64 + lane) * 16];       \
            const int4* cp_ = (const int4*)(bsqi + (gtb + t_) * 32 + h * 16);   \
            union { int4 f[4]; i32x16 v; } cu_;                                 \
            cu_.f[0] = cp_[0]; cu_.f[1] = cp_[1];                               \
            cu_.f[2] = cp_[2]; cu_.f[3] = cp_[3];                               \
            CU = cu_.v;                                                         \
        }
    #define DOT(A, CU)                                                          \
        {                                                                       \
            i32x16 c0 = __builtin_amdgcn_mfma_i32_32x32x32_i8(A[0], B00[0], CU, 0, 0, 0); \
            i32x16 c1 = __builtin_amdgcn_mfma_i32_32x32x32_i8(A[0], B01[0], CU, 0, 0, 0); \
            c0 = __builtin_amdgcn_mfma_i32_32x32x32_i8(A[1], B00[1], c0, 0, 0, 0); \
            c1 = __builtin_amdgcn_mfma_i32_32x32x32_i8(A[1], B01[1], c1, 0, 0, 0); \
            rmin00 = imin(rmin00, itree16(c0));                                 \
            rmin01 = imin(rmin01, itree16(c1));                                 \
            i32x16 c2 = __builtin_amdgcn_mfma_i32_32x32x32_i8(A[0], B10[0], CU, 0, 0, 0); \
            i32x16 c3 = __builtin_amdgcn_mfma_i32_32x32x32_i8(A[0], B11[0], CU, 0, 0, 0); \
            c2 = __builtin_amdgcn_mfma_i32_32x32x32_i8(A[1], B10[1], c2, 0, 0, 0); \
            c3 = __builtin_amdgcn_mfma_i32_32x32x32_i8(A[1], B11[1], c3, 0, 0, 0); \
            rmin10 = imin(rmin10, itree16(c2));                                 \
            rmin11 = imin(rmin11, itree16(c3));                                 \
        }

    i32x4 Aa[2], Ab[2];
    i32x16 cua, cub;
    LOADT(0, Aa, cua)
    #pragma unroll 1
    for (int t = 0; t < TO_TILES; t += 2) {
        LOADT(t + 1, Ab, cub)                  // in flight over tile t
        DOT(Aa, cua)
        LOADT((t + 2) & (TO_TILES - 1), Aa, cua)   // over tile t+1
        DOT(Ab, cub)
    }

    // cross-half min, plain stores: (ts,fg) wave-unique -> no atomics
    rmin00 = imin(rmin00, __shfl_xor(rmin00, 32));
    rmin01 = imin(rmin01, __shfl_xor(rmin01, 32));
    rmin10 = imin(rmin10, __shfl_xor(rmin10, 32));
    rmin11 = imin(rmin11, __shfl_xor(rmin11, 32));
    if (lane < 32) {
        pmin[(size_t)ts * N_PTS + fgA * 64 + l31]      = rmin00;
        pmin[(size_t)ts * N_PTS + fgA * 64 + 32 + l31] = rmin01;
        pmin[(size_t)ts * N_PTS + fgB * 64 + l31]      = rmin10;
        pmin[(size_t)ts * N_PTS + fgB * 64 + 32 + l31] = rmin11;
    }
}

// ---------- finish: min over 32 splits, add a_sq, global sum --------------
__global__ __launch_bounds__(256) void finish_kernel(
        const float* __restrict__ a_sq, const int* __restrict__ pmin,
        float* __restrict__ out) {
    int r = blockIdx.x * 256 + threadIdx.x;
    int m = pmin[r];
    #pragma unroll
    for (int s = 1; s < TSPLITS; s++)
        m = imin(m, pmin[(size_t)s * N_PTS + r]);
    float v = a_sq[r] + (float)m * 0.0078125f;   // /128
    #pragma unroll
    for (int k = 1; k < 64; k <<= 1) v += __shfl_xor(v, k);
    __shared__ float red[4];
    if ((threadIdx.x & 63) == 0) red[threadIdx.x >> 6] = v;
    __syncthreads();
    if (threadIdx.x == 0)
        atomicAdd(out, red[0] + red[1] + red[2] + red[3]);
}

extern "C" void kernel_launch(void* const* d_in, const int* in_sizes, int n_in,
                              void* d_out, int out_size, void* d_ws, size_t ws_size,
                              hipStream_t stream) {
    const float* from_pts = (const float*)d_in[0];
    const float* to_pts   = (const float*)d_in[1];
    char* ws = (char*)d_ws;
    float* a_sq = (float*)ws;                                  //  64 KB
    int*   bsqi = (int*)(ws + (64 << 10));                     //  64 KB
    int*   pmin = (int*)(ws + (128 << 10));                    //   2 MB
    char*  BfQ  = ws + (128 << 10) + (2 << 20);                //   1 MB
    char*  AtoQ = ws + (128 << 10) + (3 << 20);                //   1 MB

    prep_kernel<<<(2 * N_PTS * 8) / 256, 256, 0, stream>>>(
        from_pts, to_pts, a_sq, bsqi, BfQ, AtoQ, (float*)d_out);
    main_kernel<<<NBLOCKS, 512, 0, stream>>>(BfQ, AtoQ, bsqi, pmin);
    finish_kernel<<<N_PTS / 256, 256, 0, stream>>>(a_sq, pmin, (float*)d_out);
}